// Round 3
// baseline (51.282 us; speedup 1.0000x reference)
//
#include <hip/hip_runtime.h>
#include <math.h>

#define N_   256
#define B_   256
#define DM   1024
#define KH   1280   // n*5
#define PI24 0.13089969389957473f
#define SPLITS 16
#define KCHUNK 80   // KH / SPLITS
#define BK 16

// ws layout (floats):
//   wT : [0, 131072)  65536 float2 (w0, relu(S)) transposed [j][i]
//   Hp : [131072, 131072 + SPLITS*B_*DM)  split-K partials
#define WS_WT   0
#define WS_PART 131072

// ---------------------------------------------------------------------------
// K1: prep (blocks 0..63) + fp32 GEMM h = history @ W1, BM=BN=128, split-K=16
// grid 256 x 512
// ---------------------------------------------------------------------------
__global__ __launch_bounds__(512, 2) void k1_gemm_prep(
    const float* __restrict__ hist, const float* __restrict__ W1,
    const float* __restrict__ pw,   const float* __restrict__ S,
    float* __restrict__ ws) {
    __shared__ union {
        struct { float As[BK][132]; float Bs[BK][132]; } g;  // As[k][m], Bs[k][n]
        float2 tile[32][33];
    } sh;

    float2* wT = (float2*)(ws + WS_WT);
    float*  Hp = ws + WS_PART;

    int bid = blockIdx.x;
    int tid = threadIdx.x;

    // ---- prep: w0 = sigmoid(p0-p1), s = relu(S), store transposed [j][i] ----
    if (bid < 64) {
        int i0 = (bid >> 3) * 32, j0 = (bid & 7) * 32;
#pragma unroll
        for (int rep = 0; rep < 2; ++rep) {
            int idx = rep * 512 + tid;
            int r = idx >> 5, c = idx & 31;          // r: local i, c: local j
            float2 p = *(const float2*)&pw[((i0 + r) * N_ + j0 + c) * 2];
            float sv = S[(i0 + r) * N_ + j0 + c];
            float w0 = 1.f / (1.f + __expf(p.y - p.x));
            sh.tile[r][c] = make_float2(w0, fmaxf(sv, 0.f));
        }
        __syncthreads();
#pragma unroll
        for (int rep = 0; rep < 2; ++rep) {
            int idx = rep * 512 + tid;
            int r = idx >> 5, c = idx & 31;          // r: local j, c: local i
            wT[(j0 + r) * N_ + i0 + c] = sh.tile[c][r];
        }
        // gemm loop's first __syncthreads protects the LDS reuse
    }

    // ---- gemm: 16 tiles (2x8 of 128x128) x 16 k-splits ----
    int tile = bid & 15, ks = bid >> 4;
    int m0 = (tile & 1) * 128, n0 = (tile >> 1) * 128, k0 = ks * KCHUNK;

    int aRow = tid >> 2, aCol = (tid & 3) * 4;       // A: 128 rows x 16 k
    int bRow = tid >> 5, bCol = (tid & 31) * 4;      // B: 16 k x 128 n
    int ty = tid >> 4, tx = tid & 15;                // C: (ty*4 rows) x (tx*8 cols)

    float4 aV, bV;
    aV = *(const float4*)&hist[(m0 + aRow) * KH + k0 + aCol];
    bV = *(const float4*)&W1[(k0 + bRow) * DM + n0 + bCol];

    float acc[4][8];
#pragma unroll
    for (int r = 0; r < 4; r++)
#pragma unroll
        for (int c = 0; c < 8; c++) acc[r][c] = 0.f;

    const int NT = KCHUNK / BK;  // 5
    for (int t = 0; t < NT; ++t) {
        __syncthreads();
        {
            const float* av = (const float*)&aV;
#pragma unroll
            for (int c = 0; c < 4; c++) sh.g.As[aCol + c][aRow] = av[c];
            *(float4*)&sh.g.Bs[bRow][bCol] = bV;
        }
        __syncthreads();
        if (t + 1 < NT) {
            int k = k0 + (t + 1) * BK;
            aV = *(const float4*)&hist[(m0 + aRow) * KH + k + aCol];
            bV = *(const float4*)&W1[(k + bRow) * DM + n0 + bCol];
        }
#pragma unroll
        for (int kk = 0; kk < BK; ++kk) {
            float4 a  = *(const float4*)&sh.g.As[kk][ty * 4];
            float4 b0 = *(const float4*)&sh.g.Bs[kk][tx * 8];
            float4 b1 = *(const float4*)&sh.g.Bs[kk][tx * 8 + 4];
            float av[4] = {a.x, a.y, a.z, a.w};
            float bv[8] = {b0.x, b0.y, b0.z, b0.w, b1.x, b1.y, b1.z, b1.w};
#pragma unroll
            for (int r = 0; r < 4; r++)
#pragma unroll
                for (int c = 0; c < 8; c++)
                    acc[r][c] = fmaf(av[r], bv[c], acc[r][c]);
        }
    }
    float* P = Hp + (size_t)ks * (B_ * DM);
#pragma unroll
    for (int r = 0; r < 4; r++) {
        float4 v0 = make_float4(acc[r][0], acc[r][1], acc[r][2], acc[r][3]);
        float4 v1 = make_float4(acc[r][4], acc[r][5], acc[r][6], acc[r][7]);
        *(float4*)&P[(m0 + ty * 4 + r) * DM + n0 + tx * 8]     = v0;
        *(float4*)&P[(m0 + ty * 4 + r) * DM + n0 + tx * 8 + 4] = v1;
    }
}

// ---------------------------------------------------------------------------
// K2: head (sum partials, LN, ReLU, W2, tanh/sigmoid -> LDS consts) + main.
// One block per batch, 512 threads. grid 256 x 512
// ---------------------------------------------------------------------------
__global__ __launch_bounds__(512, 2) void k2_head_main(
    const float* __restrict__ ws_ro, const float* __restrict__ b1,
    const float* __restrict__ lg, const float* __restrict__ lb,
    const float* __restrict__ W2, const float* __restrict__ b2,
    const float* __restrict__ phi_prev, const float* __restrict__ x2,
    float* __restrict__ out) {
    __shared__ float2 hred2[8];
    __shared__ float4 hred4[8];
    __shared__ float  cbc[8];
    __shared__ float2 xs[256];
    __shared__ float2 sred[256];

    const float2* wT = (const float2*)(ws_ro + WS_WT);
    const float*  Hp = ws_ro + WS_PART;

    int b = blockIdx.x;
    int tid = threadIdx.x;
    int lane = tid & 63, wid = tid >> 6;

    // ---- head: h = sum_s Hp[s][b] + b1, layernorm stats ----
    float2 b12 = *(const float2*)&b1[tid * 2];
    float h0 = b12.x, h1 = b12.y;
#pragma unroll
    for (int s = 0; s < SPLITS; ++s) {
        float2 p = *(const float2*)&Hp[(size_t)s * (B_ * DM) + b * DM + tid * 2];
        h0 += p.x; h1 += p.y;
    }
    float s1 = h0 + h1, s2 = h0 * h0 + h1 * h1;
#pragma unroll
    for (int off = 32; off > 0; off >>= 1) {
        s1 += __shfl_down(s1, off);
        s2 += __shfl_down(s2, off);
    }
    if (lane == 0) hred2[wid] = make_float2(s1, s2);
    __syncthreads();
    float ms = 0.f, vs = 0.f;
#pragma unroll
    for (int w = 0; w < 8; ++w) { ms += hred2[w].x; vs += hred2[w].y; }
    float mean = ms * (1.f / DM);
    float var  = vs * (1.f / DM) - mean * mean;
    float rstd = rsqrtf(var + 1e-5f);

    float2 g2  = *(const float2*)&lg[tid * 2];
    float2 be2 = *(const float2*)&lb[tid * 2];
    float y0 = fmaxf((h0 - mean) * rstd * g2.x + be2.x, 0.f);
    float y1 = fmaxf((h1 - mean) * rstd * g2.y + be2.y, 0.f);
    float4 wA = *(const float4*)&W2[(tid * 2) * 4];
    float4 wB = *(const float4*)&W2[(tid * 2 + 1) * 4];
    float4 pv;
    pv.x = y0 * wA.x + y1 * wB.x;
    pv.y = y0 * wA.y + y1 * wB.y;
    pv.z = y0 * wA.z + y1 * wB.z;
    pv.w = y0 * wA.w + y1 * wB.w;
#pragma unroll
    for (int off = 32; off > 0; off >>= 1) {
        pv.x += __shfl_down(pv.x, off);
        pv.y += __shfl_down(pv.y, off);
        pv.z += __shfl_down(pv.z, off);
        pv.w += __shfl_down(pv.w, off);
    }
    if (lane == 0) hred4[wid] = pv;
    __syncthreads();
    if (tid == 0) {
        float P0 = b2[0], P1 = b2[1], P2 = b2[2], P3 = b2[3];
#pragma unroll
        for (int w = 0; w < 8; ++w) {
            float4 o = hred4[w];
            P0 += o.x; P1 += o.y; P2 += o.z; P3 += o.w;
        }
        float dphi0 = tanhf(P0) * PI24;
        float dphi1 = tanhf(P2) * PI24;
        float phi0 = phi_prev[b * 2 + 0] + dphi0;
        float phi1 = phi_prev[b * 2 + 1] + dphi1;
        float r0 = 1.f / (1.f + expf(-P1));
        float r1 = 1.f / (1.f + expf(-P3));
        out[B_ * N_ * 2 + b * 2 + 0] = phi0;
        out[B_ * N_ * 2 + b * 2 + 1] = phi1;
        out[B_ * N_ * 2 + B_ * 2 + b * 2 + 0] = dphi0;
        out[B_ * N_ * 2 + B_ * 2 + b * 2 + 1] = dphi1;
        cbc[0] = phi0 - phi1;   // delta
        cbc[1] = r1;
        cbc[2] = r0 - r1;       // dr
        cbc[3] = cosf(phi1);
        cbc[4] = sinf(phi1);
    }
    // ---- main ----
    ((float*)xs)[tid] = x2[b * (N_ * 2) + tid];
    __syncthreads();
    float delta = cbc[0], r1v = cbc[1], drv = cbc[2], c1 = cbc[3], sn1 = cbc[4];

    int i = tid & 255, jh = tid >> 8;
    int jbase = jh * 128;
    const float2* wp = &wT[jbase * N_ + i];

    float ar0 = 0.f, ai0 = 0.f, ar1 = 0.f, ai1 = 0.f;
#pragma unroll 4
    for (int jj = 0; jj < 128; jj += 2) {
        {
            float2 w = wp[(size_t)jj * N_];
            float r = fmaf(w.x, drv, r1v);
            float g = r * w.y;                       // in (0, 0.4)
            float u = g * g;
            // 1.1*tanh(g) = g*(1.1 + u*(-1.1/3 + u*(2.2/15 - u*1.1*17/315)))
            float tp = fmaf(u, fmaf(u, fmaf(u, -0.059365079f, 0.14666667f),
                                    -0.36666667f), 1.1f);
            float A = g * tp;
            float ang = w.x * delta;
            float sn = __sinf(ang);
            float cs = __cosf(ang);
            float2 xv = xs[jbase + jj];
            float ar = A * cs, as_ = A * sn;
            ar0 = fmaf(ar, xv.x, ar0); ar0 = fmaf(-as_, xv.y, ar0);
            ai0 = fmaf(as_, xv.x, ai0); ai0 = fmaf(ar, xv.y, ai0);
        }
        {
            float2 w = wp[(size_t)(jj + 1) * N_];
            float r = fmaf(w.x, drv, r1v);
            float g = r * w.y;
            float u = g * g;
            float tp = fmaf(u, fmaf(u, fmaf(u, -0.059365079f, 0.14666667f),
                                    -0.36666667f), 1.1f);
            float A = g * tp;
            float ang = w.x * delta;
            float sn = __sinf(ang);
            float cs = __cosf(ang);
            float2 xv = xs[jbase + jj + 1];
            float ar = A * cs, as_ = A * sn;
            ar1 = fmaf(ar, xv.x, ar1); ar1 = fmaf(-as_, xv.y, ar1);
            ai1 = fmaf(as_, xv.x, ai1); ai1 = fmaf(ar, xv.y, ai1);
        }
    }
    float accr = ar0 + ar1, acci = ai0 + ai1;
    if (jh) sred[i] = make_float2(accr, acci);
    __syncthreads();
    if (!jh) {
        float2 o = sred[i];
        accr += o.x; acci += o.y;
        float outr = c1 * accr - sn1 * acci;
        float outi = sn1 * accr + c1 * acci;
        ((float2*)out)[b * N_ + i] = make_float2(outr, outi);
    }
}

// ---------------------------------------------------------------------------
extern "C" void kernel_launch(void* const* d_in, const int* in_sizes, int n_in,
                              void* d_out, int out_size, void* d_ws, size_t ws_size,
                              hipStream_t stream) {
    const float* x_2ch    = (const float*)d_in[0];
    const float* history  = (const float*)d_in[1];
    const float* phi_prev = (const float*)d_in[2];
    const float* S        = (const float*)d_in[3];
    const float* W1       = (const float*)d_in[4];
    const float* b1       = (const float*)d_in[5];
    const float* ln_g     = (const float*)d_in[6];
    const float* ln_b     = (const float*)d_in[7];
    const float* W2       = (const float*)d_in[8];
    const float* b2       = (const float*)d_in[9];
    const float* path_w   = (const float*)d_in[10];

    float* out = (float*)d_out;
    float* ws  = (float*)d_ws;

    k1_gemm_prep<<<256, 512, 0, stream>>>(history, W1, path_w, S, ws);
    k2_head_main<<<256, 512, 0, stream>>>(ws, b1, ln_g, ln_b, W2, b2,
                                          phi_prev, x_2ch, out);
}